// Round 1
// 408.623 us; speedup vs baseline: 1.0825x; 1.0825x over previous
//
#include <hip/hip_runtime.h>

// Problem constants (from reference)
#define B_     8
#define A_     60000
#define C_     150        // 1 + 10+19+39+69+12
#define G_     20
#define T_     5
#define ROWS   21         // G+1 (row 0 = pad/zero row)
#define NANCH  (B_ * A_)          // 480000
#define NTOT   (B_ * A_ * C_)     // 72,000,000
#define NCHUNK (NTOT / 4)         // 18,000,000
#define TABN   (B_ * ROWS * C_)   // 25200
#define BETA_  (1.0f / 9.0f)
#define NBLK   8192
#define TPB    256

// ---------------------------------------------------------------------------
// Kernel 1: build the 0/1 label table tab[b][g][c].
//   c==0       : label for the binary head = (g>0)
//   c in head i: 1 iff any of the T gt labels for (b, g-1, head i) equals class
//   g==0       : all zeros (pad row; covers labels_bin in {-1,0})
// ---------------------------------------------------------------------------
__global__ void build_table(const int* __restrict__ gt_labels,
                            float* __restrict__ tab) {
    int i = blockIdx.x * blockDim.x + threadIdx.x;
    if (i >= TABN) return;
    int c  = i % C_;
    int bg = i / C_;
    int g  = bg % ROWS;
    int b  = bg / ROWS;
    float v = 0.0f;
    if (g > 0) {
        if (c == 0) {
            v = 1.0f;
        } else {
            int cc = c - 1;   // head offsets: 0,10,29,68,137 ; sizes 10,19,39,69,12
            int head, k;
            if      (cc < 10)  { head = 0; k = cc; }
            else if (cc < 29)  { head = 1; k = cc - 10; }
            else if (cc < 68)  { head = 2; k = cc - 29; }
            else if (cc < 137) { head = 3; k = cc - 68; }
            else               { head = 4; k = cc - 137; }
            const int* lp = gt_labels + ((b * G_ + (g - 1)) * 5 + head) * T_;
            v = (lp[0] == k || lp[1] == k || lp[2] == k ||
                 lp[3] == k || lp[4] == k) ? 1.0f : 0.0f;
        }
    }
    tab[i] = v;
}

// Block-wide sum; result valid only in threadIdx.x == 0. Block = 256 (4 waves).
__device__ __forceinline__ float block_reduce_sum(float v, float* sm) {
    #pragma unroll
    for (int off = 32; off > 0; off >>= 1) v += __shfl_down(v, off, 64);
    int lane = threadIdx.x & 63, w = threadIdx.x >> 6;
    if (lane == 0) sm[w] = v;
    __syncthreads();
    float r = 0.0f;
    if (threadIdx.x == 0) r = sm[0] + sm[1] + sm[2] + sm[3];
    __syncthreads();
    return r;
}

__device__ __forceinline__ float sl1(float n) {
    return (n < BETA_) ? (0.5f / BETA_) * n * n : n - 0.5f * BETA_;
}

// Focal term for one element, label L in {0,1}, mask mf in {0,1}.
// s = (2L-1)x ; term = mf * (0.75 - 0.5L) * (1-sigmoid(s))^2 * log(1+exp(-s))
__device__ __forceinline__ float focal_term(float x, float L, float mf) {
    float s     = (L + L - 1.0f) * x;
    float t     = __expf(-s);
    float denom = 1.0f + t;
    float om    = t * __builtin_amdgcn_rcpf(denom);   // 1 - sigmoid(s)
    float ld    = __logf(denom);                      // log(1 + exp(-s))
    return mf * fmaf(L, -0.5f, 0.75f) * (om * om) * ld;
}

// Process one float4 chunk of confidence. Wave-uniform two-path:
//  - if ALL 64 lanes see labels {0,0}: closed-form L=0, mask=1 (no gathers)
//  - else: general table path for the WHOLE wave (correct for l<=0 too,
//    since row 0 of tab is all zeros and mask kills l==-1)
__device__ __forceinline__ float process_chunk(float4 x, int a, int c,
                                               int l0, int l1,
                                               const float* __restrict__ tab) {
    float acc = 0.0f;
    float xs[4] = {x.x, x.y, x.z, x.w};
    if (!__any((l0 | l1) != 0)) {
        // ---- fast path: whole wave has label 0, mask 1 (w = 0.75) ----
        #pragma unroll
        for (int j = 0; j < 4; ++j) {
            float t     = __expf(xs[j]);                       // exp(x)
            float denom = 1.0f + t;
            float om    = t * __builtin_amdgcn_rcpf(denom);    // sigmoid(x)
            acc += 0.75f * (om * om) * __logf(denom);
        }
    } else {
        // ---- general path (~27% of waves): per-element table gather ----
        int   b0   = a / A_;
        int   row0 = (b0 * ROWS + max(l0, 0)) * C_;
        float m0   = (l0 > -1) ? 1.0f : 0.0f;
        int   row1 = row0;
        float m1   = m0;
        if (c + 3 >= C_) {                 // chunk spans into anchor a+1
            int b1 = (a + 1) / A_;
            row1 = (b1 * ROWS + max(l1, 0)) * C_;
            m1   = (l1 > -1) ? 1.0f : 0.0f;
        }
        #pragma unroll
        for (int j = 0; j < 4; ++j) {
            int cj = c + j;
            int rb; float mf;
            if (cj < C_) { rb = row0 + cj;       mf = m0; }
            else         { rb = row1 + cj - C_;  mf = m1; }
            acc += focal_term(xs[j], tab[rb], mf);
        }
    }
    return acc;
}

// ---------------------------------------------------------------------------
// Kernel 2 (fused): smooth-L1 regression + positive count + focal cls sum.
// Writes per-block partials {reg, cls, cnt} -> no atomics, no pre-zeroing.
// ---------------------------------------------------------------------------
__global__ __launch_bounds__(TPB) void fused_kernel(
        const float* __restrict__ conf,
        const float* __restrict__ pred, const float* __restrict__ gtl,
        const int*   __restrict__ lb,   const float* __restrict__ tab,
        float* __restrict__ partials) {
    __shared__ float sm[4];
    float reg = 0.0f, cls = 0.0f, cnt = 0.0f;
    const int tid    = blockIdx.x * blockDim.x + threadIdx.x;
    const int stride = gridDim.x * blockDim.x;

    // ---- regression over anchors (5% positives gather pred/gt float4) ----
    for (int a = tid; a < NANCH; a += stride) {
        int l = lb[a];
        if (l > 0) {
            cnt += 1.0f;
            float4 p = ((const float4*)pred)[a];
            float4 g = ((const float4*)gtl)[a];
            reg += sl1(fabsf(p.x - g.x)) + sl1(fabsf(p.y - g.y)) +
                   sl1(fabsf(p.z - g.z)) + sl1(fabsf(p.w - g.w));
        }
    }

    // ---- focal cls over 18M float4 chunks, unroll-2 across grid stride ----
    const float4* cp = (const float4*)conf;
    int ch = tid;
    for (; ch + stride < NCHUNK; ch += 2 * stride) {
        const int chA = ch, chB = ch + stride;
        // hoist all loads of both chunks for MLP
        float4 xA = cp[chA];
        float4 xB = cp[chB];
        int eA = chA * 4, aA = eA / C_, cA = eA - aA * C_;
        int eB = chB * 4, aB = eB / C_, cB = eB - aB * C_;
        int lA0 = lb[aA];
        int lA1 = (cA + 3 >= C_) ? lb[aA + 1] : lA0;
        int lB0 = lb[aB];
        int lB1 = (cB + 3 >= C_) ? lb[aB + 1] : lB0;
        cls += process_chunk(xA, aA, cA, lA0, lA1, tab);
        cls += process_chunk(xB, aB, cB, lB0, lB1, tab);
    }
    if (ch < NCHUNK) {
        float4 x = cp[ch];
        int e = ch * 4, a = e / C_, c = e - a * C_;
        int l0 = lb[a];
        int l1 = (c + 3 >= C_) ? lb[a + 1] : l0;
        cls += process_chunk(x, a, c, l0, l1, tab);
    }

    float rb = block_reduce_sum(reg, sm);
    float cb = block_reduce_sum(cls, sm);
    float nb = block_reduce_sum(cnt, sm);
    if (threadIdx.x == 0) {
        float4 w; w.x = rb; w.y = cb; w.z = nb; w.w = 0.0f;
        ((float4*)partials)[blockIdx.x] = w;
    }
}

// ---------------------------------------------------------------------------
// Kernel 3: reduce per-block partials, write the two scalar outputs.
// ---------------------------------------------------------------------------
__global__ __launch_bounds__(TPB) void finalize(
        const float* __restrict__ partials, float* __restrict__ out) {
    __shared__ float sm[4];
    float r = 0.0f, c = 0.0f, n = 0.0f;
    for (int i = threadIdx.x; i < NBLK; i += TPB) {
        float4 p = ((const float4*)partials)[i];
        r += p.x; c += p.y; n += p.z;
    }
    r = block_reduce_sum(r, sm);
    c = block_reduce_sum(c, sm);
    n = block_reduce_sum(n, sm);
    if (threadIdx.x == 0) {
        float np = fmaxf(1.0f, n);
        out[0] = r / (np * 4.0f);
        out[1] = c / (np * 6.0f);
    }
}

extern "C" void kernel_launch(void* const* d_in, const int* in_sizes, int n_in,
                              void* d_out, int out_size, void* d_ws, size_t ws_size,
                              hipStream_t stream) {
    const float* conf = (const float*)d_in[0];
    const float* pred = (const float*)d_in[1];
    const float* gt   = (const float*)d_in[2];
    const int*   gtl  = (const int*)d_in[3];
    // d_in[4] = counts: unused by the reference computation
    const int*   lb   = (const int*)d_in[5];
    float* out      = (float*)d_out;
    float* partials = (float*)d_ws;                 // NBLK float4 = 128 KB
    float* tab      = (float*)d_ws + 4 * NBLK;      // 25200 floats (100 KB)

    build_table<<<(TABN + TPB - 1) / TPB, TPB, 0, stream>>>(gtl, tab);
    fused_kernel<<<NBLK, TPB, 0, stream>>>(conf, pred, gt, lb, tab, partials);
    finalize<<<1, TPB, 0, stream>>>(partials, out);
}

// Round 2
// 401.655 us; speedup vs baseline: 1.1012x; 1.0173x over previous
//
#include <hip/hip_runtime.h>

// Problem constants (from reference)
#define B_     8
#define A_     60000
#define C_     150        // 1 + 10+19+39+69+12
#define G_     20
#define T_     5
#define ROWS   21         // G+1 (row 0 = pad/zero row)
#define NANCH  (B_ * A_)          // 480000
#define NTOT   (B_ * A_ * C_)     // 72,000,000
#define NCHUNK (NTOT / 4)         // 18,000,000
#define TABN   (B_ * ROWS * C_)   // 25200
#define BETA_  (1.0f / 9.0f)
#define NBLK   8192
#define TPB    256

typedef float f4 __attribute__((ext_vector_type(4)));

// ---------------------------------------------------------------------------
// Kernel 1: build the 0/1 label table tab[b][g][c].
//   c==0       : label for the binary head = (g>0)
//   c in head i: 1 iff any of the T gt labels for (b, g-1, head i) equals class
//   g==0       : all zeros (pad row; covers labels_bin in {-1,0})
// ---------------------------------------------------------------------------
__global__ void build_table(const int* __restrict__ gt_labels,
                            float* __restrict__ tab) {
    int i = blockIdx.x * blockDim.x + threadIdx.x;
    if (i >= TABN) return;
    int c  = i % C_;
    int bg = i / C_;
    int g  = bg % ROWS;
    int b  = bg / ROWS;
    float v = 0.0f;
    if (g > 0) {
        if (c == 0) {
            v = 1.0f;
        } else {
            int cc = c - 1;   // head offsets: 0,10,29,68,137 ; sizes 10,19,39,69,12
            int head, k;
            if      (cc < 10)  { head = 0; k = cc; }
            else if (cc < 29)  { head = 1; k = cc - 10; }
            else if (cc < 68)  { head = 2; k = cc - 29; }
            else if (cc < 137) { head = 3; k = cc - 68; }
            else               { head = 4; k = cc - 137; }
            const int* lp = gt_labels + ((b * G_ + (g - 1)) * 5 + head) * T_;
            v = (lp[0] == k || lp[1] == k || lp[2] == k ||
                 lp[3] == k || lp[4] == k) ? 1.0f : 0.0f;
        }
    }
    tab[i] = v;
}

// Block-wide sum; result valid only in threadIdx.x == 0. Block = 256 (4 waves).
__device__ __forceinline__ float block_reduce_sum(float v, float* sm) {
    #pragma unroll
    for (int off = 32; off > 0; off >>= 1) v += __shfl_down(v, off, 64);
    int lane = threadIdx.x & 63, w = threadIdx.x >> 6;
    if (lane == 0) sm[w] = v;
    __syncthreads();
    float r = 0.0f;
    if (threadIdx.x == 0) r = sm[0] + sm[1] + sm[2] + sm[3];
    __syncthreads();
    return r;
}

__device__ __forceinline__ float sl1(float n) {
    return (n < BETA_) ? (0.5f / BETA_) * n * n : n - 0.5f * BETA_;
}

// Focal term for one element, label L in {0,1}, mask mf in {0,1}.
// s = (2L-1)x ; term = mf * (0.75 - 0.5L) * (1-sigmoid(s))^2 * log(1+exp(-s))
__device__ __forceinline__ float focal_term(float x, float L, float mf) {
    float s     = (L + L - 1.0f) * x;
    float t     = __expf(-s);
    float denom = 1.0f + t;
    float om    = t * __builtin_amdgcn_rcpf(denom);   // 1 - sigmoid(s)
    float ld    = __logf(denom);                      // log(1 + exp(-s))
    return mf * fmaf(L, -0.5f, 0.75f) * (om * om) * ld;
}

// Process one float4 chunk of confidence. Wave-uniform two-path:
//  - if ALL 64 lanes see labels {0,0}: closed-form L=0, mask=1 (no gathers)
//  - else: general table path for the WHOLE wave (correct for l<=0 too,
//    since row 0 of tab is all zeros and mask kills l==-1)
__device__ __forceinline__ float process_chunk(f4 x, int a, int c,
                                               int l0, int l1,
                                               const float* __restrict__ tab) {
    float acc = 0.0f;
    float xs[4] = {x.x, x.y, x.z, x.w};
    if (!__any((l0 | l1) != 0)) {
        // ---- fast path: whole wave has label 0, mask 1 (w = 0.75) ----
        #pragma unroll
        for (int j = 0; j < 4; ++j) {
            float t     = __expf(xs[j]);                       // exp(x)
            float denom = 1.0f + t;
            float om    = t * __builtin_amdgcn_rcpf(denom);    // sigmoid(x)
            acc += 0.75f * (om * om) * __logf(denom);
        }
    } else {
        // ---- general path (~27% of waves): per-element table gather ----
        int   b0   = a / A_;
        int   row0 = (b0 * ROWS + max(l0, 0)) * C_;
        float m0   = (l0 > -1) ? 1.0f : 0.0f;
        int   row1 = row0;
        float m1   = m0;
        if (c + 3 >= C_) {                 // chunk spans into anchor a+1
            int b1 = (a + 1) / A_;
            row1 = (b1 * ROWS + max(l1, 0)) * C_;
            m1   = (l1 > -1) ? 1.0f : 0.0f;
        }
        #pragma unroll
        for (int j = 0; j < 4; ++j) {
            int cj = c + j;
            int rb; float mf;
            if (cj < C_) { rb = row0 + cj;       mf = m0; }
            else         { rb = row1 + cj - C_;  mf = m1; }
            acc += focal_term(xs[j], tab[rb], mf);
        }
    }
    return acc;
}

// ---------------------------------------------------------------------------
// Kernel 2 (fused): smooth-L1 regression + positive count + focal cls sum.
// Writes per-block partials {reg, cls, cnt} -> no atomics, no pre-zeroing.
// cls loop: unroll-4 across grid stride, all loads hoisted (64 B/thread in
// flight), nontemporal conf stream (read-once).
// ---------------------------------------------------------------------------
__global__ __launch_bounds__(TPB) void fused_kernel(
        const float* __restrict__ conf,
        const float* __restrict__ pred, const float* __restrict__ gtl,
        const int*   __restrict__ lb,   const float* __restrict__ tab,
        float* __restrict__ partials) {
    __shared__ float sm[4];
    float reg = 0.0f, cls = 0.0f, cnt = 0.0f;
    const int tid    = blockIdx.x * blockDim.x + threadIdx.x;
    const int stride = gridDim.x * blockDim.x;

    // ---- regression over anchors (5% positives gather pred/gt float4) ----
    for (int a = tid; a < NANCH; a += stride) {
        int l = lb[a];
        if (l > 0) {
            cnt += 1.0f;
            float4 p = ((const float4*)pred)[a];
            float4 g = ((const float4*)gtl)[a];
            reg += sl1(fabsf(p.x - g.x)) + sl1(fabsf(p.y - g.y)) +
                   sl1(fabsf(p.z - g.z)) + sl1(fabsf(p.w - g.w));
        }
    }

    // ---- focal cls over 18M float4 chunks ----
    const f4* cp = (const f4*)conf;
    int ch = tid;
    for (; ch + 3 * stride < NCHUNK; ch += 4 * stride) {
        const int c0 = ch, c1 = ch + stride, c2 = ch + 2 * stride,
                  c3 = ch + 3 * stride;
        // hoist all conf loads (nontemporal: stream, read-once)
        f4 x0 = __builtin_nontemporal_load(cp + c0);
        f4 x1 = __builtin_nontemporal_load(cp + c1);
        f4 x2 = __builtin_nontemporal_load(cp + c2);
        f4 x3 = __builtin_nontemporal_load(cp + c3);
        // hoist all label loads
        int e0 = c0 * 4, a0 = e0 / C_, cc0 = e0 - a0 * C_;
        int e1 = c1 * 4, a1 = e1 / C_, cc1 = e1 - a1 * C_;
        int e2 = c2 * 4, a2 = e2 / C_, cc2 = e2 - a2 * C_;
        int e3 = c3 * 4, a3 = e3 / C_, cc3 = e3 - a3 * C_;
        int l00 = lb[a0], l01 = (cc0 + 3 >= C_) ? lb[a0 + 1] : l00;
        int l10 = lb[a1], l11 = (cc1 + 3 >= C_) ? lb[a1 + 1] : l10;
        int l20 = lb[a2], l21 = (cc2 + 3 >= C_) ? lb[a2 + 1] : l20;
        int l30 = lb[a3], l31 = (cc3 + 3 >= C_) ? lb[a3 + 1] : l30;
        cls += process_chunk(x0, a0, cc0, l00, l01, tab);
        cls += process_chunk(x1, a1, cc1, l10, l11, tab);
        cls += process_chunk(x2, a2, cc2, l20, l21, tab);
        cls += process_chunk(x3, a3, cc3, l30, l31, tab);
    }
    for (; ch < NCHUNK; ch += stride) {
        f4 x = __builtin_nontemporal_load(cp + ch);
        int e = ch * 4, a = e / C_, c = e - a * C_;
        int l0 = lb[a];
        int l1 = (c + 3 >= C_) ? lb[a + 1] : l0;
        cls += process_chunk(x, a, c, l0, l1, tab);
    }

    float rb = block_reduce_sum(reg, sm);
    float cb = block_reduce_sum(cls, sm);
    float nb = block_reduce_sum(cnt, sm);
    if (threadIdx.x == 0) {
        float4 w; w.x = rb; w.y = cb; w.z = nb; w.w = 0.0f;
        ((float4*)partials)[blockIdx.x] = w;
    }
}

// ---------------------------------------------------------------------------
// Kernel 3: reduce per-block partials, write the two scalar outputs.
// ---------------------------------------------------------------------------
__global__ __launch_bounds__(TPB) void finalize(
        const float* __restrict__ partials, float* __restrict__ out) {
    __shared__ float sm[4];
    float r = 0.0f, c = 0.0f, n = 0.0f;
    for (int i = threadIdx.x; i < NBLK; i += TPB) {
        float4 p = ((const float4*)partials)[i];
        r += p.x; c += p.y; n += p.z;
    }
    r = block_reduce_sum(r, sm);
    c = block_reduce_sum(c, sm);
    n = block_reduce_sum(n, sm);
    if (threadIdx.x == 0) {
        float np = fmaxf(1.0f, n);
        out[0] = r / (np * 4.0f);
        out[1] = c / (np * 6.0f);
    }
}

extern "C" void kernel_launch(void* const* d_in, const int* in_sizes, int n_in,
                              void* d_out, int out_size, void* d_ws, size_t ws_size,
                              hipStream_t stream) {
    const float* conf = (const float*)d_in[0];
    const float* pred = (const float*)d_in[1];
    const float* gt   = (const float*)d_in[2];
    const int*   gtl  = (const int*)d_in[3];
    // d_in[4] = counts: unused by the reference computation
    const int*   lb   = (const int*)d_in[5];
    float* out      = (float*)d_out;
    float* partials = (float*)d_ws;                 // NBLK float4 = 128 KB
    float* tab      = (float*)d_ws + 4 * NBLK;      // 25200 floats (100 KB)

    build_table<<<(TABN + TPB - 1) / TPB, TPB, 0, stream>>>(gtl, tab);
    fused_kernel<<<NBLK, TPB, 0, stream>>>(conf, pred, gt, lb, tab, partials);
    finalize<<<1, TPB, 0, stream>>>(partials, out);
}